// Round 2
// baseline (457.348 us; speedup 1.0000x reference)
//
#include <hip/hip_runtime.h>
#include <hip/hip_bf16.h>
#include <math.h>

#define DEVINL static __device__ __forceinline__

typedef short bf16x8 __attribute__((ext_vector_type(8)));
typedef float f32x4 __attribute__((ext_vector_type(4)));

// B=2, T=2048, C=1024, H=16, D=64
constexpr int TT = 2048, CC = 1024, HH = 16, DD = 64;

DEVINL ushort f2bf(float f) {
  union { float f; unsigned u; } v; v.f = f;
  unsigned r = v.u + 0x7FFFu + ((v.u >> 16) & 1u);
  return (ushort)(r >> 16);
}

DEVINL void split2(float v, ushort& hi, ushort& lo) {
  ushort h = f2bf(v);
  union { unsigned u; float f; } hf; hf.u = (unsigned)h << 16;
  hi = h;
  lo = f2bf(v - hf.f);
}

DEVINL void gload_lds16(const void* g, void* s) {
  __builtin_amdgcn_global_load_lds(
      (const __attribute__((address_space(1))) void*)g,
      (__attribute__((address_space(3))) void*)s, 16, 0, 0);
}

// ---- weight transpose + cast: fp32 [K,N] -> bf16 [N,K] ----
__global__ __launch_bounds__(256) void transpose_cast(
    const float* __restrict__ in, ushort* __restrict__ out, int K, int N) {
  __shared__ float tile[32][33];
  int n0 = blockIdx.x * 32, k0 = blockIdx.y * 32;
  int tx = threadIdx.x & 31, ty = threadIdx.x >> 5;  // 32x8
  #pragma unroll
  for (int i = 0; i < 32; i += 8)
    tile[ty + i][tx] = in[(size_t)(k0 + ty + i) * N + n0 + tx];
  __syncthreads();
  #pragma unroll
  for (int i = 0; i < 32; i += 8)
    out[(size_t)(n0 + ty + i) * K + k0 + tx] = f2bf(tile[tx][ty + i]);
}

// ---- weight transpose + SPLIT cast: fp32 [K,N] -> bf16 hi[N,K] + lo[N,K] ----
__global__ __launch_bounds__(256) void transpose_cast_split(
    const float* __restrict__ in, ushort* __restrict__ oh,
    ushort* __restrict__ ol, int K, int N) {
  __shared__ float tile[32][33];
  int n0 = blockIdx.x * 32, k0 = blockIdx.y * 32;
  int tx = threadIdx.x & 31, ty = threadIdx.x >> 5;
  #pragma unroll
  for (int i = 0; i < 32; i += 8)
    tile[ty + i][tx] = in[(size_t)(k0 + ty + i) * N + n0 + tx];
  __syncthreads();
  #pragma unroll
  for (int i = 0; i < 32; i += 8) {
    ushort h, l;
    split2(tile[tx][ty + i], h, l);
    size_t idx = (size_t)(n0 + ty + i) * K + k0 + tx;
    oh[idx] = h; ol[idx] = l;
  }
}

// ---- LayerNorm. SPLIT=1: write hi+lo bf16 pair; SPLIT=0: bf16 only. ----
template <int SPLIT>
__global__ __launch_bounds__(256) void ln_cast(
    const float* __restrict__ x, const float* __restrict__ g,
    const float* __restrict__ bta, ushort* __restrict__ oh,
    ushort* __restrict__ ol) {
  int row = blockIdx.x, t = threadIdx.x;
  float4 v = ((const float4*)(x + (size_t)row * CC))[t];
  float s = v.x + v.y + v.z + v.w;
  float s2 = v.x * v.x + v.y * v.y + v.z * v.z + v.w * v.w;
  #pragma unroll
  for (int o = 32; o >= 1; o >>= 1) { s += __shfl_xor(s, o); s2 += __shfl_xor(s2, o); }
  __shared__ float ss[4], ssq[4];
  int w = t >> 6;
  if ((t & 63) == 0) { ss[w] = s; ssq[w] = s2; }
  __syncthreads();
  s = ss[0] + ss[1] + ss[2] + ss[3];
  s2 = ssq[0] + ssq[1] + ssq[2] + ssq[3];
  float mu = s * (1.0f / CC);
  float rs = rsqrtf(s2 * (1.0f / CC) - mu * mu + 1e-5f);
  float4 gv = ((const float4*)g)[t];
  float4 bv = ((const float4*)bta)[t];
  float y0 = (v.x - mu) * rs * gv.x + bv.x;
  float y1 = (v.y - mu) * rs * gv.y + bv.y;
  float y2 = (v.z - mu) * rs * gv.z + bv.z;
  float y3 = (v.w - mu) * rs * gv.w + bv.w;
  if constexpr (SPLIT) {
    ushort4 h4, l4;
    split2(y0, h4.x, l4.x); split2(y1, h4.y, l4.y);
    split2(y2, h4.z, l4.z); split2(y3, h4.w, l4.w);
    ((ushort4*)(oh + (size_t)row * CC))[t] = h4;
    ((ushort4*)(ol + (size_t)row * CC))[t] = l4;
  } else {
    ushort4 o4;
    o4.x = f2bf(y0); o4.y = f2bf(y1); o4.z = f2bf(y2); o4.w = f2bf(y3);
    ((ushort4*)(oh + (size_t)row * CC))[t] = o4;
  }
}

// ---- Plain GEMM: C[M,N] = A[M,K](bf16) * Bt[N,K]^T + bias.
// EPI 1: exact GELU -> bf16. EPI 2: + res (fp32) -> fp32.
template <int EPI, int N, int K>
__global__ __launch_bounds__(256) void gemm_bt(
    const ushort* __restrict__ A, const ushort* __restrict__ Bt,
    const float* __restrict__ bias, const float* __restrict__ res,
    void* __restrict__ outp) {
  __shared__ __align__(16) ushort As[128 * 64];
  __shared__ __align__(16) ushort Bs[128 * 64];
  const int bm0 = blockIdx.y * 128, bn0 = blockIdx.x * 128;
  const int t = threadIdx.x, w = t >> 6, l = t & 63, lg = l >> 4, lr = l & 15;
  const int wr = w >> 1, wc = w & 1;
  const int srow = t >> 3, sc = t & 7;
  f32x4 acc[4][4] = {};
  for (int k0 = 0; k0 < K; k0 += 64) {
    #pragma unroll
    for (int q = 0; q < 4; ++q) {
      int row = q * 32 + srow;
      int gc = sc ^ (row & 7);  // inverse-swizzle global source (rule 21)
      gload_lds16(A + (size_t)(bm0 + row) * K + k0 + gc * 8, As + row * 64 + sc * 8);
      gload_lds16(Bt + (size_t)(bn0 + row) * K + k0 + gc * 8, Bs + row * 64 + sc * 8);
    }
    __syncthreads();
    #pragma unroll
    for (int ks = 0; ks < 2; ++ks) {
      bf16x8 af[4], bfr[4];
      #pragma unroll
      for (int mi = 0; mi < 4; ++mi) {
        int row = wr * 64 + mi * 16 + lr;
        af[mi] = *(const bf16x8*)(As + row * 64 + (((ks * 4 + lg) ^ (row & 7)) << 3));
      }
      #pragma unroll
      for (int ni = 0; ni < 4; ++ni) {
        int row = wc * 64 + ni * 16 + lr;
        bfr[ni] = *(const bf16x8*)(Bs + row * 64 + (((ks * 4 + lg) ^ (row & 7)) << 3));
      }
      #pragma unroll
      for (int mi = 0; mi < 4; ++mi)
        #pragma unroll
        for (int ni = 0; ni < 4; ++ni)
          acc[mi][ni] = __builtin_amdgcn_mfma_f32_16x16x32_bf16(af[mi], bfr[ni], acc[mi][ni], 0, 0, 0);
    }
    __syncthreads();
  }
  #pragma unroll
  for (int mi = 0; mi < 4; ++mi) {
    #pragma unroll
    for (int ni = 0; ni < 4; ++ni) {
      int gc = bn0 + wc * 64 + ni * 16 + lr;
      float bv = bias[gc];
      #pragma unroll
      for (int r = 0; r < 4; ++r) {
        int gr = bm0 + wr * 64 + mi * 16 + lg * 4 + r;
        float v = acc[mi][ni][r] + bv;
        if constexpr (EPI == 1) {
          float gl = 0.5f * v * (1.0f + erff(v * 0.70710678118654752f));
          ((ushort*)outp)[(size_t)gr * N + gc] = f2bf(gl);
        } else {
          ((float*)outp)[(size_t)gr * N + gc] = res[(size_t)gr * N + gc] + v;
        }
      }
    }
  }
}

// ---- QKV GEMM, split-bf16 emulated-fp32: acc += Ah*Bh + Ah*Bl + Al*Bh.
// Epilogue: cols [0,C) -> q hi/lo; [C,2C) -> k hi/lo; [2C,3C) -> vt scatter.
__global__ __launch_bounds__(256) void gemm_qkv_split(
    const ushort* __restrict__ Ah, const ushort* __restrict__ Al,
    const ushort* __restrict__ Bh, const ushort* __restrict__ Bl,
    const float* __restrict__ bias,
    ushort* __restrict__ qh, ushort* __restrict__ ql,
    ushort* __restrict__ kh, ushort* __restrict__ kl,
    ushort* __restrict__ vt) {
  __shared__ __align__(16) ushort Ash[128 * 64], Asl[128 * 64];
  __shared__ __align__(16) ushort Bsh[128 * 64], Bsl[128 * 64];
  const int bm0 = blockIdx.y * 128, bn0 = blockIdx.x * 128;
  const int t = threadIdx.x, w = t >> 6, l = t & 63, lg = l >> 4, lr = l & 15;
  const int wr = w >> 1, wc = w & 1;
  const int srow = t >> 3, sc = t & 7;
  f32x4 acc[4][4] = {};
  for (int k0 = 0; k0 < 1024; k0 += 64) {
    #pragma unroll
    for (int q = 0; q < 4; ++q) {
      int row = q * 32 + srow;
      int gc = sc ^ (row & 7);
      size_t ga = (size_t)(bm0 + row) * 1024 + k0 + gc * 8;
      size_t gb = (size_t)(bn0 + row) * 1024 + k0 + gc * 8;
      int so = row * 64 + sc * 8;
      gload_lds16(Ah + ga, Ash + so);
      gload_lds16(Al + ga, Asl + so);
      gload_lds16(Bh + gb, Bsh + so);
      gload_lds16(Bl + gb, Bsl + so);
    }
    __syncthreads();
    #pragma unroll
    for (int ks = 0; ks < 2; ++ks) {
      bf16x8 ah[4], al[4], bh[4], bl[4];
      #pragma unroll
      for (int mi = 0; mi < 4; ++mi) {
        int row = wr * 64 + mi * 16 + lr;
        int off = row * 64 + (((ks * 4 + lg) ^ (row & 7)) << 3);
        ah[mi] = *(const bf16x8*)(Ash + off);
        al[mi] = *(const bf16x8*)(Asl + off);
      }
      #pragma unroll
      for (int ni = 0; ni < 4; ++ni) {
        int row = wc * 64 + ni * 16 + lr;
        int off = row * 64 + (((ks * 4 + lg) ^ (row & 7)) << 3);
        bh[ni] = *(const bf16x8*)(Bsh + off);
        bl[ni] = *(const bf16x8*)(Bsl + off);
      }
      #pragma unroll
      for (int mi = 0; mi < 4; ++mi)
        #pragma unroll
        for (int ni = 0; ni < 4; ++ni) {
          acc[mi][ni] = __builtin_amdgcn_mfma_f32_16x16x32_bf16(ah[mi], bh[ni], acc[mi][ni], 0, 0, 0);
          acc[mi][ni] = __builtin_amdgcn_mfma_f32_16x16x32_bf16(ah[mi], bl[ni], acc[mi][ni], 0, 0, 0);
          acc[mi][ni] = __builtin_amdgcn_mfma_f32_16x16x32_bf16(al[mi], bh[ni], acc[mi][ni], 0, 0, 0);
        }
    }
    __syncthreads();
  }
  #pragma unroll
  for (int mi = 0; mi < 4; ++mi) {
    #pragma unroll
    for (int ni = 0; ni < 4; ++ni) {
      int gc = bn0 + wc * 64 + ni * 16 + lr;
      float bv = bias[gc];
      int sec = gc >> 10, cc = gc & 1023;
      #pragma unroll
      for (int r = 0; r < 4; ++r) {
        int gr = bm0 + wr * 64 + mi * 16 + lg * 4 + r;
        float v = acc[mi][ni][r] + bv;
        size_t idx = (size_t)gr * 1024 + cc;
        if (sec == 0) {
          ushort h, lo; split2(v, h, lo); qh[idx] = h; ql[idx] = lo;
        } else if (sec == 1) {
          ushort h, lo; split2(v, h, lo); kh[idx] = h; kl[idx] = lo;
        } else {  // V -> vt[B,H,D,T]
          int hh = cc >> 6, dd = cc & 63;
          int bb = gr >> 11, tk = gr & (TT - 1);
          vt[(((size_t)bb * HH + hh) * DD + dd) * TT + tk] = f2bf(v);
        }
      }
    }
  }
}

// ---- Flash attention, split-bf16 QK^T: grid (T/128, H, B); 4 waves x 32 q-rows ----
__global__ __launch_bounds__(256) void flash_attn(
    const ushort* __restrict__ qh_, const ushort* __restrict__ ql_,
    const ushort* __restrict__ kh_, const ushort* __restrict__ kl_,
    const ushort* __restrict__ vt, ushort* __restrict__ att) {
  const int qt0 = blockIdx.x * 128, h = blockIdx.y, b = blockIdx.z;
  const int t = threadIdx.x, w = t >> 6, l = t & 63, lg = l >> 4, lr = l & 15;
  __shared__ __align__(16) ushort Qh[128 * 64], Ql[128 * 64];
  __shared__ __align__(16) ushort Kh[64 * 64], Kl[64 * 64];
  __shared__ __align__(16) ushort VTs[64 * 64];
  __shared__ __align__(16) ushort Ps[4][32 * 64];
  const int srow = t >> 3, sc = t & 7;
  #pragma unroll
  for (int q = 0; q < 4; ++q) {
    int row = q * 32 + srow;
    int gc = sc ^ (row & 7);
    size_t ga = ((size_t)(b * TT + qt0 + row)) * CC + h * DD + gc * 8;
    gload_lds16(qh_ + ga, Qh + row * 64 + sc * 8);
    gload_lds16(ql_ + ga, Ql + row * 64 + sc * 8);
  }
  f32x4 o[2][4] = {};
  float mrow[2][4], lsum[2][4];
  #pragma unroll
  for (int mi = 0; mi < 2; ++mi)
    #pragma unroll
    for (int r = 0; r < 4; ++r) { mrow[mi][r] = -3.0e38f; lsum[mi][r] = 0.f; }

  for (int kv0 = 0; kv0 < TT; kv0 += 64) {
    #pragma unroll
    for (int q = 0; q < 2; ++q) {
      int row = q * 32 + srow;
      int gc = sc ^ (row & 7);
      size_t gk = ((size_t)(b * TT + kv0 + row)) * CC + h * DD + gc * 8;
      int so = row * 64 + sc * 8;
      gload_lds16(kh_ + gk, Kh + so);
      gload_lds16(kl_ + gk, Kl + so);
      gload_lds16(vt + (((size_t)b * HH + h) * DD + row) * TT + kv0 + gc * 8, VTs + so);
    }
    __syncthreads();
    f32x4 s[2][4] = {};
    #pragma unroll
    for (int ks = 0; ks < 2; ++ks) {
      bf16x8 qhf[2], qlf[2], khf[4], klf[4];
      #pragma unroll
      for (int mi = 0; mi < 2; ++mi) {
        int row = w * 32 + mi * 16 + lr;
        int off = row * 64 + (((ks * 4 + lg) ^ (row & 7)) << 3);
        qhf[mi] = *(const bf16x8*)(Qh + off);
        qlf[mi] = *(const bf16x8*)(Ql + off);
      }
      #pragma unroll
      for (int ni = 0; ni < 4; ++ni) {
        int row = ni * 16 + lr;
        int off = row * 64 + (((ks * 4 + lg) ^ (row & 7)) << 3);
        khf[ni] = *(const bf16x8*)(Kh + off);
        klf[ni] = *(const bf16x8*)(Kl + off);
      }
      #pragma unroll
      for (int mi = 0; mi < 2; ++mi)
        #pragma unroll
        for (int ni = 0; ni < 4; ++ni) {
          s[mi][ni] = __builtin_amdgcn_mfma_f32_16x16x32_bf16(qhf[mi], khf[ni], s[mi][ni], 0, 0, 0);
          s[mi][ni] = __builtin_amdgcn_mfma_f32_16x16x32_bf16(qhf[mi], klf[ni], s[mi][ni], 0, 0, 0);
          s[mi][ni] = __builtin_amdgcn_mfma_f32_16x16x32_bf16(qlf[mi], khf[ni], s[mi][ni], 0, 0, 0);
        }
    }
    ushort* Pw = Ps[w];
    #pragma unroll
    for (int mi = 0; mi < 2; ++mi) {
      #pragma unroll
      for (int r = 0; r < 4; ++r) {
        float v0 = s[mi][0][r] * 0.125f, v1 = s[mi][1][r] * 0.125f;
        float v2 = s[mi][2][r] * 0.125f, v3 = s[mi][3][r] * 0.125f;
        float rm = fmaxf(fmaxf(v0, v1), fmaxf(v2, v3));
        #pragma unroll
        for (int msk = 1; msk <= 8; msk <<= 1) rm = fmaxf(rm, __shfl_xor(rm, msk));
        float mo = mrow[mi][r];
        float mn = fmaxf(mo, rm);
        float corr = exp2f((mo - mn) * 1.44269504f);
        mrow[mi][r] = mn;
        #pragma unroll
        for (int di = 0; di < 4; ++di) o[mi][di][r] *= corr;
        float p0 = exp2f((v0 - mn) * 1.44269504f);
        float p1 = exp2f((v1 - mn) * 1.44269504f);
        float p2 = exp2f((v2 - mn) * 1.44269504f);
        float p3 = exp2f((v3 - mn) * 1.44269504f);
        float ps = p0 + p1 + p2 + p3;
        #pragma unroll
        for (int msk = 1; msk <= 8; msk <<= 1) ps += __shfl_xor(ps, msk);
        lsum[mi][r] = lsum[mi][r] * corr + ps;
        int prow = mi * 16 + lg * 4 + r, rx = prow & 7;
        Pw[prow * 64 + ((((0 + (lr >> 3)) ^ rx)) << 3) + (lr & 7)] = f2bf(p0);
        Pw[prow * 64 + ((((2 + (lr >> 3)) ^ rx)) << 3) + (lr & 7)] = f2bf(p1);
        Pw[prow * 64 + ((((4 + (lr >> 3)) ^ rx)) << 3) + (lr & 7)] = f2bf(p2);
        Pw[prow * 64 + ((((6 + (lr >> 3)) ^ rx)) << 3) + (lr & 7)] = f2bf(p3);
      }
    }
    #pragma unroll
    for (int ks = 0; ks < 2; ++ks) {
      bf16x8 pf[2], vf[4];
      #pragma unroll
      for (int mi = 0; mi < 2; ++mi) {
        int row = mi * 16 + lr;
        pf[mi] = *(const bf16x8*)(Pw + row * 64 + (((ks * 4 + lg) ^ (row & 7)) << 3));
      }
      #pragma unroll
      for (int di = 0; di < 4; ++di) {
        int row = di * 16 + lr;
        vf[di] = *(const bf16x8*)(VTs + row * 64 + (((ks * 4 + lg) ^ (row & 7)) << 3));
      }
      #pragma unroll
      for (int mi = 0; mi < 2; ++mi)
        #pragma unroll
        for (int di = 0; di < 4; ++di)
          o[mi][di] = __builtin_amdgcn_mfma_f32_16x16x32_bf16(pf[mi], vf[di], o[mi][di], 0, 0, 0);
    }
    __syncthreads();
  }
  #pragma unroll
  for (int mi = 0; mi < 2; ++mi)
    #pragma unroll
    for (int di = 0; di < 4; ++di)
      #pragma unroll
      for (int r = 0; r < 4; ++r) {
        int token = qt0 + w * 32 + mi * 16 + lg * 4 + r;
        int col = h * DD + di * 16 + lr;
        att[((size_t)b * TT + token) * CC + col] = f2bf(o[mi][di][r] / lsum[mi][r]);
      }
}

extern "C" void kernel_launch(void* const* d_in, const int* in_sizes, int n_in,
                              void* d_out, int out_size, void* d_ws, size_t ws_size,
                              hipStream_t stream) {
  const float* x      = (const float*)d_in[0];
  const float* w_qkv  = (const float*)d_in[1];
  const float* b_qkv  = (const float*)d_in[2];
  const float* w_proj = (const float*)d_in[3];
  const float* b_proj = (const float*)d_in[4];
  const float* ln1_g  = (const float*)d_in[5];
  const float* ln1_b  = (const float*)d_in[6];
  const float* w_fc   = (const float*)d_in[7];
  const float* b_fc   = (const float*)d_in[8];
  const float* w_out  = (const float*)d_in[9];
  const float* b_out  = (const float*)d_in[10];
  const float* ln2_g  = (const float*)d_in[11];
  const float* ln2_b  = (const float*)d_in[12];

  char* ws = (char*)d_ws;
  // Weights (persistent through their consumer GEMM):
  ushort* wqkv_hi = (ushort*)(ws);              // [3072,1024] 6291456
  ushort* wqkv_lo = (ushort*)(ws + 6291456);    // 6291456
  ushort* wproj_t = (ushort*)(ws + 12582912);   // [1024,1024] 2097152
  ushort* wfc_t   = (ushort*)(ws + 14680064);   // [4096,1024] 8388608
  ushort* wout_t  = (ushort*)(ws + 23068672);   // [1024,4096] 8388608
  // LN1 out (dead after QKV GEMM; slots reused for att / LN2 out):
  ushort* h_hi    = (ushort*)(ws + 31457280);   // 8388608
  ushort* h_lo    = (ushort*)(ws + 39845888);   // 8388608
  ushort* att_bf  = h_hi;                       // reuse (flash output)
  ushort* h2_bf   = h_lo;                       // reuse (LN2 output)
  // Q/K split + V^T (dead after attention; slot reused for fc output):
  ushort* q_hi    = (ushort*)(ws + 48234496);   // 8388608
  ushort* q_lo    = (ushort*)(ws + 56623104);   // 8388608
  ushort* k_hi    = (ushort*)(ws + 65011712);   // 8388608
  ushort* k_lo    = (ushort*)(ws + 73400320);   // 8388608
  ushort* vt_bf   = (ushort*)(ws + 81788928);   // [B,H,D,T] 8388608
  ushort* t_bf    = (ushort*)(ws + 48234496);   // [4096,4096] 33554432 (reuse)
  float*  x1      = (float*)(ws + 90177536);    // [4096,1024] fp32 16777216
  // total ws: 106954752 bytes

  transpose_cast_split<<<dim3(96, 32), 256, 0, stream>>>(w_qkv, wqkv_hi, wqkv_lo, 1024, 3072);
  transpose_cast<<<dim3(32, 32), 256, 0, stream>>>(w_proj, wproj_t, 1024, 1024);
  transpose_cast<<<dim3(128, 32), 256, 0, stream>>>(w_fc, wfc_t, 1024, 4096);
  transpose_cast<<<dim3(32, 128), 256, 0, stream>>>(w_out, wout_t, 4096, 1024);

  ln_cast<1><<<4096, 256, 0, stream>>>(x, ln1_g, ln1_b, h_hi, h_lo);
  gemm_qkv_split<<<dim3(24, 32), 256, 0, stream>>>(h_hi, h_lo, wqkv_hi, wqkv_lo, b_qkv,
                                                   q_hi, q_lo, k_hi, k_lo, vt_bf);
  flash_attn<<<dim3(16, 16, 2), 256, 0, stream>>>(q_hi, q_lo, k_hi, k_lo, vt_bf, att_bf);
  gemm_bt<2, 1024, 1024><<<dim3(8, 32), 256, 0, stream>>>(att_bf, wproj_t, b_proj, x, x1);
  ln_cast<0><<<4096, 256, 0, stream>>>(x1, ln2_g, ln2_b, h2_bf, nullptr);
  gemm_bt<1, 4096, 1024><<<dim3(32, 32), 256, 0, stream>>>(h2_bf, wfc_t, b_fc, nullptr, t_bf);
  gemm_bt<2, 1024, 4096><<<dim3(8, 32), 256, 0, stream>>>(t_bf, wout_t, b_out, x1, (float*)d_out);
}

// Round 3
// 365.474 us; speedup vs baseline: 1.2514x; 1.2514x over previous
//
#include <hip/hip_runtime.h>
#include <hip/hip_bf16.h>
#include <math.h>

#define DEVINL static __device__ __forceinline__

typedef _Float16 f16x8 __attribute__((ext_vector_type(8)));
typedef _Float16 f16x4 __attribute__((ext_vector_type(4)));
typedef float f32x4 __attribute__((ext_vector_type(4)));

// B=2, T=2048, C=1024, H=16, D=64
constexpr int TT = 2048, CC = 1024, HH = 16, DD = 64;

DEVINL void gload_lds16(const void* g, void* s) {
  __builtin_amdgcn_global_load_lds(
      (const __attribute__((address_space(1))) void*)g,
      (__attribute__((address_space(3))) void*)s, 16, 0, 0);
}

// ---- weight transpose + cast: fp32 [K,N] -> fp16 [N,K] ----
__global__ __launch_bounds__(256) void transpose_cast(
    const float* __restrict__ in, _Float16* __restrict__ out, int K, int N) {
  __shared__ float tile[32][33];
  int n0 = blockIdx.x * 32, k0 = blockIdx.y * 32;
  int tx = threadIdx.x & 31, ty = threadIdx.x >> 5;  // 32x8
  #pragma unroll
  for (int i = 0; i < 32; i += 8)
    tile[ty + i][tx] = in[(size_t)(k0 + ty + i) * N + n0 + tx];
  __syncthreads();
  #pragma unroll
  for (int i = 0; i < 32; i += 8)
    out[(size_t)(n0 + ty + i) * K + k0 + tx] = (_Float16)tile[tx][ty + i];
}

// ---- LayerNorm -> fp16. One block per row of [4096, 1024]. ----
__global__ __launch_bounds__(256) void ln_cast(
    const float* __restrict__ x, const float* __restrict__ g,
    const float* __restrict__ bta, _Float16* __restrict__ out) {
  int row = blockIdx.x, t = threadIdx.x;
  float4 v = ((const float4*)(x + (size_t)row * CC))[t];
  float s = v.x + v.y + v.z + v.w;
  float s2 = v.x * v.x + v.y * v.y + v.z * v.z + v.w * v.w;
  #pragma unroll
  for (int o = 32; o >= 1; o >>= 1) { s += __shfl_xor(s, o); s2 += __shfl_xor(s2, o); }
  __shared__ float ss[4], ssq[4];
  int w = t >> 6;
  if ((t & 63) == 0) { ss[w] = s; ssq[w] = s2; }
  __syncthreads();
  s = ss[0] + ss[1] + ss[2] + ss[3];
  s2 = ssq[0] + ssq[1] + ssq[2] + ssq[3];
  float mu = s * (1.0f / CC);
  float rs = rsqrtf(s2 * (1.0f / CC) - mu * mu + 1e-5f);
  float4 gv = ((const float4*)g)[t];
  float4 bv = ((const float4*)bta)[t];
  f16x4 o4;
  o4[0] = (_Float16)((v.x - mu) * rs * gv.x + bv.x);
  o4[1] = (_Float16)((v.y - mu) * rs * gv.y + bv.y);
  o4[2] = (_Float16)((v.z - mu) * rs * gv.z + bv.z);
  o4[3] = (_Float16)((v.w - mu) * rs * gv.w + bv.w);
  ((f16x4*)(out + (size_t)row * CC))[t] = o4;
}

// ---- Plain GEMM: C[M,N] = A[M,K](fp16) * Bt[N,K]^T + bias.
// EPI 1: exact GELU -> fp16. EPI 2: + res (fp32) -> fp32.
template <int EPI, int N, int K>
__global__ __launch_bounds__(256) void gemm_bt(
    const _Float16* __restrict__ A, const _Float16* __restrict__ Bt,
    const float* __restrict__ bias, const float* __restrict__ res,
    void* __restrict__ outp) {
  __shared__ __align__(16) _Float16 As[128 * 64];
  __shared__ __align__(16) _Float16 Bs[128 * 64];
  const int bm0 = blockIdx.y * 128, bn0 = blockIdx.x * 128;
  const int t = threadIdx.x, w = t >> 6, l = t & 63, lg = l >> 4, lr = l & 15;
  const int wr = w >> 1, wc = w & 1;
  const int srow = t >> 3, sc = t & 7;
  f32x4 acc[4][4] = {};
  for (int k0 = 0; k0 < K; k0 += 64) {
    #pragma unroll
    for (int q = 0; q < 4; ++q) {
      int row = q * 32 + srow;
      int gc = sc ^ (row & 7);  // inverse-swizzle global source (rule 21)
      gload_lds16(A + (size_t)(bm0 + row) * K + k0 + gc * 8, As + row * 64 + sc * 8);
      gload_lds16(Bt + (size_t)(bn0 + row) * K + k0 + gc * 8, Bs + row * 64 + sc * 8);
    }
    __syncthreads();
    #pragma unroll
    for (int ks = 0; ks < 2; ++ks) {
      f16x8 af[4], bfr[4];
      #pragma unroll
      for (int mi = 0; mi < 4; ++mi) {
        int row = wr * 64 + mi * 16 + lr;
        af[mi] = *(const f16x8*)(As + row * 64 + (((ks * 4 + lg) ^ (row & 7)) << 3));
      }
      #pragma unroll
      for (int ni = 0; ni < 4; ++ni) {
        int row = wc * 64 + ni * 16 + lr;
        bfr[ni] = *(const f16x8*)(Bs + row * 64 + (((ks * 4 + lg) ^ (row & 7)) << 3));
      }
      #pragma unroll
      for (int mi = 0; mi < 4; ++mi)
        #pragma unroll
        for (int ni = 0; ni < 4; ++ni)
          acc[mi][ni] = __builtin_amdgcn_mfma_f32_16x16x32_f16(af[mi], bfr[ni], acc[mi][ni], 0, 0, 0);
    }
    __syncthreads();
  }
  #pragma unroll
  for (int mi = 0; mi < 4; ++mi) {
    #pragma unroll
    for (int ni = 0; ni < 4; ++ni) {
      int gc = bn0 + wc * 64 + ni * 16 + lr;
      float bv = bias[gc];
      #pragma unroll
      for (int r = 0; r < 4; ++r) {
        int gr = bm0 + wr * 64 + mi * 16 + lg * 4 + r;
        float v = acc[mi][ni][r] + bv;
        if constexpr (EPI == 1) {
          float gl = 0.5f * v * (1.0f + erff(v * 0.70710678118654752f));
          ((_Float16*)outp)[(size_t)gr * N + gc] = (_Float16)gl;
        } else {
          ((float*)outp)[(size_t)gr * N + gc] = res[(size_t)gr * N + gc] + v;
        }
      }
    }
  }
}

// ---- QKV GEMM (fp16): writes q[B,T,C], k[B,T,C], vt[B,H,D,T] ----
__global__ __launch_bounds__(256) void gemm_qkv(
    const _Float16* __restrict__ A, const _Float16* __restrict__ Bt,
    const float* __restrict__ bias,
    _Float16* __restrict__ qo, _Float16* __restrict__ ko,
    _Float16* __restrict__ vt) {
  __shared__ __align__(16) _Float16 As[128 * 64];
  __shared__ __align__(16) _Float16 Bs[128 * 64];
  const int bm0 = blockIdx.y * 128, bn0 = blockIdx.x * 128;
  const int t = threadIdx.x, w = t >> 6, l = t & 63, lg = l >> 4, lr = l & 15;
  const int wr = w >> 1, wc = w & 1;
  const int srow = t >> 3, sc = t & 7;
  f32x4 acc[4][4] = {};
  for (int k0 = 0; k0 < 1024; k0 += 64) {
    #pragma unroll
    for (int q = 0; q < 4; ++q) {
      int row = q * 32 + srow;
      int gc = sc ^ (row & 7);
      gload_lds16(A + (size_t)(bm0 + row) * 1024 + k0 + gc * 8, As + row * 64 + sc * 8);
      gload_lds16(Bt + (size_t)(bn0 + row) * 1024 + k0 + gc * 8, Bs + row * 64 + sc * 8);
    }
    __syncthreads();
    #pragma unroll
    for (int ks = 0; ks < 2; ++ks) {
      f16x8 af[4], bfr[4];
      #pragma unroll
      for (int mi = 0; mi < 4; ++mi) {
        int row = wr * 64 + mi * 16 + lr;
        af[mi] = *(const f16x8*)(As + row * 64 + (((ks * 4 + lg) ^ (row & 7)) << 3));
      }
      #pragma unroll
      for (int ni = 0; ni < 4; ++ni) {
        int row = wc * 64 + ni * 16 + lr;
        bfr[ni] = *(const f16x8*)(Bs + row * 64 + (((ks * 4 + lg) ^ (row & 7)) << 3));
      }
      #pragma unroll
      for (int mi = 0; mi < 4; ++mi)
        #pragma unroll
        for (int ni = 0; ni < 4; ++ni)
          acc[mi][ni] = __builtin_amdgcn_mfma_f32_16x16x32_f16(af[mi], bfr[ni], acc[mi][ni], 0, 0, 0);
    }
    __syncthreads();
  }
  #pragma unroll
  for (int mi = 0; mi < 4; ++mi) {
    #pragma unroll
    for (int ni = 0; ni < 4; ++ni) {
      int gc = bn0 + wc * 64 + ni * 16 + lr;
      float bv = bias[gc];
      int sec = gc >> 10, cc = gc & 1023;
      #pragma unroll
      for (int r = 0; r < 4; ++r) {
        int gr = bm0 + wr * 64 + mi * 16 + lg * 4 + r;
        float v = acc[mi][ni][r] + bv;
        if (sec == 0) {
          qo[(size_t)gr * 1024 + cc] = (_Float16)v;
        } else if (sec == 1) {
          ko[(size_t)gr * 1024 + cc] = (_Float16)v;
        } else {  // V -> vt[B,H,D,T]
          int hh = cc >> 6, dd = cc & 63;
          int bb = gr >> 11, tk = gr & (TT - 1);
          vt[(((size_t)bb * HH + hh) * DD + dd) * TT + tk] = (_Float16)v;
        }
      }
    }
  }
}

// ---- Flash attention: grid (T/64, H, B); 4 waves x 16 q-rows; Q in regs ----
__global__ __launch_bounds__(256) void flash_attn(
    const _Float16* __restrict__ qg, const _Float16* __restrict__ kg,
    const _Float16* __restrict__ vt, _Float16* __restrict__ att) {
  const int qt0 = blockIdx.x * 64, h = blockIdx.y, b = blockIdx.z;
  const int t = threadIdx.x, w = t >> 6, l = t & 63, lg = l >> 4, lr = l & 15;
  __shared__ __align__(16) _Float16 Ks[64 * 64];
  __shared__ __align__(16) _Float16 VTs[64 * 64];
  __shared__ __align__(16) _Float16 Ps[4][16 * 64];
  const int srow = t >> 3, sc = t & 7;
  const float SCL = 0.125f * 1.44269504f;  // fold 1/sqrt(D) and log2(e)
  // Q fragments in registers (A-operand layout: row = lr, k-chunk = ks*32+lg*8)
  f16x8 qf[2];
  #pragma unroll
  for (int ks = 0; ks < 2; ++ks)
    qf[ks] = *(const f16x8*)(qg + ((size_t)(b * TT + qt0 + w * 16 + lr)) * CC +
                             h * DD + ks * 32 + lg * 8);
  f32x4 o[4] = {};
  float mrow[4], lsum[4];
  #pragma unroll
  for (int r = 0; r < 4; ++r) { mrow[r] = -3.0e38f; lsum[r] = 0.f; }

  for (int kv0 = 0; kv0 < TT; kv0 += 64) {
    #pragma unroll
    for (int q = 0; q < 2; ++q) {
      int row = q * 32 + srow;
      int gc = sc ^ (row & 7);
      gload_lds16(kg + ((size_t)(b * TT + kv0 + row)) * CC + h * DD + gc * 8,
                  Ks + row * 64 + sc * 8);
      gload_lds16(vt + (((size_t)b * HH + h) * DD + row) * TT + kv0 + gc * 8,
                  VTs + row * 64 + sc * 8);
    }
    __syncthreads();
    // QK^T
    f32x4 s[4] = {};
    #pragma unroll
    for (int ks = 0; ks < 2; ++ks)
      #pragma unroll
      for (int ni = 0; ni < 4; ++ni) {
        int row = ni * 16 + lr;
        f16x8 kf = *(const f16x8*)(Ks + row * 64 + (((ks * 4 + lg) ^ (row & 7)) << 3));
        s[ni] = __builtin_amdgcn_mfma_f32_16x16x32_f16(qf[ks], kf, s[ni], 0, 0, 0);
      }
    // online softmax (exp2 domain); row = lg*4 + r
    _Float16* Pw = Ps[w];
    #pragma unroll
    for (int r = 0; r < 4; ++r) {
      float v0 = s[0][r] * SCL, v1 = s[1][r] * SCL;
      float v2 = s[2][r] * SCL, v3 = s[3][r] * SCL;
      float rm = fmaxf(fmaxf(v0, v1), fmaxf(v2, v3));
      #pragma unroll
      for (int msk = 1; msk <= 8; msk <<= 1) rm = fmaxf(rm, __shfl_xor(rm, msk));
      float mo = mrow[r];
      float mn = fmaxf(mo, rm);
      float corr = exp2f(mo - mn);
      mrow[r] = mn;
      #pragma unroll
      for (int di = 0; di < 4; ++di) o[di][r] *= corr;
      float p0 = exp2f(v0 - mn), p1 = exp2f(v1 - mn);
      float p2 = exp2f(v2 - mn), p3 = exp2f(v3 - mn);
      float ps = p0 + p1 + p2 + p3;
      #pragma unroll
      for (int msk = 1; msk <= 8; msk <<= 1) ps += __shfl_xor(ps, msk);
      lsum[r] = lsum[r] * corr + ps;
      int prow = lg * 4 + r, rx = prow & 7;
      Pw[prow * 64 + (((0 + (lr >> 3)) ^ rx) << 3) + (lr & 7)] = (_Float16)p0;
      Pw[prow * 64 + (((2 + (lr >> 3)) ^ rx) << 3) + (lr & 7)] = (_Float16)p1;
      Pw[prow * 64 + (((4 + (lr >> 3)) ^ rx) << 3) + (lr & 7)] = (_Float16)p2;
      Pw[prow * 64 + (((6 + (lr >> 3)) ^ rx) << 3) + (lr & 7)] = (_Float16)p3;
    }
    // PV (Pw is per-wave: no barrier needed; compiler orders ds_write->ds_read)
    #pragma unroll
    for (int ks = 0; ks < 2; ++ks) {
      f16x8 pf = *(const f16x8*)(Pw + lr * 64 + (((ks * 4 + lg) ^ (lr & 7)) << 3));
      #pragma unroll
      for (int di = 0; di < 4; ++di) {
        int row = di * 16 + lr;
        f16x8 vf = *(const f16x8*)(VTs + row * 64 + (((ks * 4 + lg) ^ (row & 7)) << 3));
        o[di] = __builtin_amdgcn_mfma_f32_16x16x32_f16(pf, vf, o[di], 0, 0, 0);
      }
    }
    __syncthreads();  // protect Ks/VTs before next-tile staging
  }
  #pragma unroll
  for (int r = 0; r < 4; ++r) {
    float rinv = 1.0f / lsum[r];
    int row_g = qt0 + w * 16 + lg * 4 + r;
    #pragma unroll
    for (int di = 0; di < 4; ++di)
      att[((size_t)(b * TT + row_g)) * CC + h * DD + di * 16 + lr] =
          (_Float16)(o[di][r] * rinv);
  }
}

extern "C" void kernel_launch(void* const* d_in, const int* in_sizes, int n_in,
                              void* d_out, int out_size, void* d_ws, size_t ws_size,
                              hipStream_t stream) {
  const float* x      = (const float*)d_in[0];
  const float* w_qkv  = (const float*)d_in[1];
  const float* b_qkv  = (const float*)d_in[2];
  const float* w_proj = (const float*)d_in[3];
  const float* b_proj = (const float*)d_in[4];
  const float* ln1_g  = (const float*)d_in[5];
  const float* ln1_b  = (const float*)d_in[6];
  const float* w_fc   = (const float*)d_in[7];
  const float* b_fc   = (const float*)d_in[8];
  const float* w_out  = (const float*)d_in[9];
  const float* b_out  = (const float*)d_in[10];
  const float* ln2_g  = (const float*)d_in[11];
  const float* ln2_b  = (const float*)d_in[12];

  char* ws = (char*)d_ws;
  _Float16* wqkv_t = (_Float16*)(ws);              // [3072,1024] 6291456
  _Float16* wproj_t= (_Float16*)(ws + 6291456);    // [1024,1024] -> 8388608
  _Float16* wfc_t  = (_Float16*)(ws + 8388608);    // [4096,1024] -> 16777216
  _Float16* wout_t = (_Float16*)(ws + 16777216);   // [1024,4096] -> 25165824
  _Float16* hslot  = (_Float16*)(ws + 25165824);   // 8388608: h -> att -> h2 (serial reuse)
  _Float16* qbuf   = (_Float16*)(ws + 33554432);   // 8388608
  _Float16* kbuf   = (_Float16*)(ws + 41943040);   // 8388608
  _Float16* vtbuf  = (_Float16*)(ws + 50331648);   // 8388608
  _Float16* tbuf   = (_Float16*)(ws + 33554432);   // [4096,4096] 33554432 (reuses q/k/vt, dead)
  float*    x1     = (float*)(ws + 67108864);      // fp32 16777216 -> 83886080 total

  transpose_cast<<<dim3(96, 32), 256, 0, stream>>>(w_qkv, wqkv_t, 1024, 3072);
  transpose_cast<<<dim3(32, 32), 256, 0, stream>>>(w_proj, wproj_t, 1024, 1024);
  transpose_cast<<<dim3(128, 32), 256, 0, stream>>>(w_fc, wfc_t, 1024, 4096);
  transpose_cast<<<dim3(32, 128), 256, 0, stream>>>(w_out, wout_t, 4096, 1024);

  ln_cast<<<4096, 256, 0, stream>>>(x, ln1_g, ln1_b, hslot);
  gemm_qkv<<<dim3(24, 32), 256, 0, stream>>>(hslot, wqkv_t, b_qkv, qbuf, kbuf, vtbuf);
  flash_attn<<<dim3(32, 16, 2), 256, 0, stream>>>(qbuf, kbuf, vtbuf, hslot);
  gemm_bt<2, 1024, 1024><<<dim3(8, 32), 256, 0, stream>>>(hslot, wproj_t, b_proj, x, x1);
  ln_cast<<<4096, 256, 0, stream>>>(x1, ln2_g, ln2_b, hslot);
  gemm_bt<1, 4096, 1024><<<dim3(32, 32), 256, 0, stream>>>(hslot, wfc_t, b_fc, nullptr, tbuf);
  gemm_bt<2, 1024, 4096><<<dim3(8, 32), 256, 0, stream>>>(tbuf, wout_t, b_out, x1, (float*)d_out);
}

// Round 4
// 343.357 us; speedup vs baseline: 1.3320x; 1.0644x over previous
//
#include <hip/hip_runtime.h>
#include <hip/hip_bf16.h>
#include <math.h>

#define DEVINL static __device__ __forceinline__

typedef _Float16 f16x8 __attribute__((ext_vector_type(8)));
typedef _Float16 f16x4 __attribute__((ext_vector_type(4)));
typedef float f32x4 __attribute__((ext_vector_type(4)));

// B=2, T=2048, C=1024, H=16, D=64
constexpr int TT = 2048, CC = 1024, HH = 16, DD = 64;

DEVINL void gload_lds16(const void* g, void* s) {
  __builtin_amdgcn_global_load_lds(
      (const __attribute__((address_space(1))) void*)g,
      (__attribute__((address_space(3))) void*)s, 16, 0, 0);
}

// ---- weight transpose + cast: fp32 [K,N] -> fp16 [N,K] ----
__global__ __launch_bounds__(256) void transpose_cast(
    const float* __restrict__ in, _Float16* __restrict__ out, int K, int N) {
  __shared__ float tile[32][33];
  int n0 = blockIdx.x * 32, k0 = blockIdx.y * 32;
  int tx = threadIdx.x & 31, ty = threadIdx.x >> 5;  // 32x8
  #pragma unroll
  for (int i = 0; i < 32; i += 8)
    tile[ty + i][tx] = in[(size_t)(k0 + ty + i) * N + n0 + tx];
  __syncthreads();
  #pragma unroll
  for (int i = 0; i < 32; i += 8)
    out[(size_t)(n0 + ty + i) * K + k0 + tx] = (_Float16)tile[tx][ty + i];
}

// ---- LayerNorm -> fp16. One block per row of [4096, 1024]. ----
__global__ __launch_bounds__(256) void ln_cast(
    const float* __restrict__ x, const float* __restrict__ g,
    const float* __restrict__ bta, _Float16* __restrict__ out) {
  int row = blockIdx.x, t = threadIdx.x;
  float4 v = ((const float4*)(x + (size_t)row * CC))[t];
  float s = v.x + v.y + v.z + v.w;
  float s2 = v.x * v.x + v.y * v.y + v.z * v.z + v.w * v.w;
  #pragma unroll
  for (int o = 32; o >= 1; o >>= 1) { s += __shfl_xor(s, o); s2 += __shfl_xor(s2, o); }
  __shared__ float ss[4], ssq[4];
  int w = t >> 6;
  if ((t & 63) == 0) { ss[w] = s; ssq[w] = s2; }
  __syncthreads();
  s = ss[0] + ss[1] + ss[2] + ss[3];
  s2 = ssq[0] + ssq[1] + ssq[2] + ssq[3];
  float mu = s * (1.0f / CC);
  float rs = rsqrtf(s2 * (1.0f / CC) - mu * mu + 1e-5f);
  float4 gv = ((const float4*)g)[t];
  float4 bv = ((const float4*)bta)[t];
  f16x4 o4;
  o4[0] = (_Float16)((v.x - mu) * rs * gv.x + bv.x);
  o4[1] = (_Float16)((v.y - mu) * rs * gv.y + bv.y);
  o4[2] = (_Float16)((v.z - mu) * rs * gv.z + bv.z);
  o4[3] = (_Float16)((v.w - mu) * rs * gv.w + bv.w);
  ((f16x4*)(out + (size_t)row * CC))[t] = o4;
}

// ---- Plain GEMM: C[M,N] = A[M,K](fp16) * Bt[N,K]^T + bias.
// EPI 1: exact GELU -> fp16. EPI 2: + res (fp32) -> fp32.
template <int EPI, int N, int K>
__global__ __launch_bounds__(256) void gemm_bt(
    const _Float16* __restrict__ A, const _Float16* __restrict__ Bt,
    const float* __restrict__ bias, const float* __restrict__ res,
    void* __restrict__ outp) {
  __shared__ __align__(16) _Float16 As[128 * 64];
  __shared__ __align__(16) _Float16 Bs[128 * 64];
  const int bm0 = blockIdx.y * 128, bn0 = blockIdx.x * 128;
  const int t = threadIdx.x, w = t >> 6, l = t & 63, lg = l >> 4, lr = l & 15;
  const int wr = w >> 1, wc = w & 1;
  const int srow = t >> 3, sc = t & 7;
  f32x4 acc[4][4] = {};
  for (int k0 = 0; k0 < K; k0 += 64) {
    #pragma unroll
    for (int q = 0; q < 4; ++q) {
      int row = q * 32 + srow;
      int gc = sc ^ (row & 7);  // inverse-swizzle global source (rule 21)
      gload_lds16(A + (size_t)(bm0 + row) * K + k0 + gc * 8, As + row * 64 + sc * 8);
      gload_lds16(Bt + (size_t)(bn0 + row) * K + k0 + gc * 8, Bs + row * 64 + sc * 8);
    }
    __syncthreads();
    #pragma unroll
    for (int ks = 0; ks < 2; ++ks) {
      f16x8 af[4], bfr[4];
      #pragma unroll
      for (int mi = 0; mi < 4; ++mi) {
        int row = wr * 64 + mi * 16 + lr;
        af[mi] = *(const f16x8*)(As + row * 64 + (((ks * 4 + lg) ^ (row & 7)) << 3));
      }
      #pragma unroll
      for (int ni = 0; ni < 4; ++ni) {
        int row = wc * 64 + ni * 16 + lr;
        bfr[ni] = *(const f16x8*)(Bs + row * 64 + (((ks * 4 + lg) ^ (row & 7)) << 3));
      }
      #pragma unroll
      for (int mi = 0; mi < 4; ++mi)
        #pragma unroll
        for (int ni = 0; ni < 4; ++ni)
          acc[mi][ni] = __builtin_amdgcn_mfma_f32_16x16x32_f16(af[mi], bfr[ni], acc[mi][ni], 0, 0, 0);
    }
    __syncthreads();
  }
  #pragma unroll
  for (int mi = 0; mi < 4; ++mi) {
    #pragma unroll
    for (int ni = 0; ni < 4; ++ni) {
      int gc = bn0 + wc * 64 + ni * 16 + lr;
      float bv = bias[gc];
      #pragma unroll
      for (int r = 0; r < 4; ++r) {
        int gr = bm0 + wr * 64 + mi * 16 + lg * 4 + r;
        float v = acc[mi][ni][r] + bv;
        if constexpr (EPI == 1) {
          float gl = 0.5f * v * (1.0f + erff(v * 0.70710678118654752f));
          ((_Float16*)outp)[(size_t)gr * N + gc] = (_Float16)gl;
        } else {
          ((float*)outp)[(size_t)gr * N + gc] = res[(size_t)gr * N + gc] + v;
        }
      }
    }
  }
}

// ---- QKV GEMM (fp16): writes q[B,T,C] (pre-scaled by 0.125*log2e), k[B,T,C],
// vt[B,H,D,T] ----
__global__ __launch_bounds__(256) void gemm_qkv(
    const _Float16* __restrict__ A, const _Float16* __restrict__ Bt,
    const float* __restrict__ bias,
    _Float16* __restrict__ qo, _Float16* __restrict__ ko,
    _Float16* __restrict__ vt) {
  __shared__ __align__(16) _Float16 As[128 * 64];
  __shared__ __align__(16) _Float16 Bs[128 * 64];
  const int bm0 = blockIdx.y * 128, bn0 = blockIdx.x * 128;
  const int t = threadIdx.x, w = t >> 6, l = t & 63, lg = l >> 4, lr = l & 15;
  const int wr = w >> 1, wc = w & 1;
  const int srow = t >> 3, sc = t & 7;
  f32x4 acc[4][4] = {};
  for (int k0 = 0; k0 < 1024; k0 += 64) {
    #pragma unroll
    for (int q = 0; q < 4; ++q) {
      int row = q * 32 + srow;
      int gc = sc ^ (row & 7);
      gload_lds16(A + (size_t)(bm0 + row) * 1024 + k0 + gc * 8, As + row * 64 + sc * 8);
      gload_lds16(Bt + (size_t)(bn0 + row) * 1024 + k0 + gc * 8, Bs + row * 64 + sc * 8);
    }
    __syncthreads();
    #pragma unroll
    for (int ks = 0; ks < 2; ++ks) {
      f16x8 af[4], bfr[4];
      #pragma unroll
      for (int mi = 0; mi < 4; ++mi) {
        int row = wr * 64 + mi * 16 + lr;
        af[mi] = *(const f16x8*)(As + row * 64 + (((ks * 4 + lg) ^ (row & 7)) << 3));
      }
      #pragma unroll
      for (int ni = 0; ni < 4; ++ni) {
        int row = wc * 64 + ni * 16 + lr;
        bfr[ni] = *(const f16x8*)(Bs + row * 64 + (((ks * 4 + lg) ^ (row & 7)) << 3));
      }
      #pragma unroll
      for (int mi = 0; mi < 4; ++mi)
        #pragma unroll
        for (int ni = 0; ni < 4; ++ni)
          acc[mi][ni] = __builtin_amdgcn_mfma_f32_16x16x32_f16(af[mi], bfr[ni], acc[mi][ni], 0, 0, 0);
    }
    __syncthreads();
  }
  const float QSCL = 0.125f * 1.44269504f;  // fold 1/sqrt(D)*log2(e) into Q
  #pragma unroll
  for (int mi = 0; mi < 4; ++mi) {
    #pragma unroll
    for (int ni = 0; ni < 4; ++ni) {
      int gc = bn0 + wc * 64 + ni * 16 + lr;
      float bv = bias[gc];
      int sec = gc >> 10, cc = gc & 1023;
      #pragma unroll
      for (int r = 0; r < 4; ++r) {
        int gr = bm0 + wr * 64 + mi * 16 + lg * 4 + r;
        float v = acc[mi][ni][r] + bv;
        if (sec == 0) {
          qo[(size_t)gr * 1024 + cc] = (_Float16)(v * QSCL);
        } else if (sec == 1) {
          ko[(size_t)gr * 1024 + cc] = (_Float16)v;
        } else {  // V -> vt[B,H,D,T]
          int hh = cc >> 6, dd = cc & 63;
          int bb = gr >> 11, tk = gr & (TT - 1);
          vt[(((size_t)bb * HH + hh) * DD + dd) * TT + tk] = (_Float16)v;
        }
      }
    }
  }
}

// ---- Flash attention: grid (T/64, H, B); 4 waves x 16 q-rows; Q in regs.
// Defer-max (THR=8 exp2-domain), denominator via ones-MFMA, double-buffered KV.
__global__ __launch_bounds__(256) void flash_attn(
    const _Float16* __restrict__ qg, const _Float16* __restrict__ kg,
    const _Float16* __restrict__ vt, _Float16* __restrict__ att) {
  const int qt0 = blockIdx.x * 64, h = blockIdx.y, b = blockIdx.z;
  const int t = threadIdx.x, w = t >> 6, l = t & 63, lg = l >> 4, lr = l & 15;
  __shared__ __align__(16) _Float16 Ks[2][64 * 64];
  __shared__ __align__(16) _Float16 VTs[2][64 * 64];
  __shared__ __align__(16) _Float16 Ps[4][16 * 64];
  const int srow = t >> 3, sc = t & 7;
  // Q fragments in registers (A-operand: row=lr, k-chunk = ks*32+lg*8); pre-scaled.
  f16x8 qf[2];
  #pragma unroll
  for (int ks = 0; ks < 2; ++ks)
    qf[ks] = *(const f16x8*)(qg + ((size_t)(b * TT + qt0 + w * 16 + lr)) * CC +
                             h * DD + ks * 32 + lg * 8);
  f32x4 o[4] = {};
  f32x4 osum = {};  // row-sum accumulator via ones-MFMA (rescaled with o)
  float mrow[4];
  #pragma unroll
  for (int r = 0; r < 4; ++r) mrow[r] = -3.0e38f;
  const f16x8 ones = {(_Float16)1, (_Float16)1, (_Float16)1, (_Float16)1,
                      (_Float16)1, (_Float16)1, (_Float16)1, (_Float16)1};

  auto STAGE = [&](int bufi, int kv0) {
    #pragma unroll
    for (int q = 0; q < 2; ++q) {
      int row = q * 32 + srow;
      int gc = sc ^ (row & 7);
      gload_lds16(kg + ((size_t)(b * TT + kv0 + row)) * CC + h * DD + gc * 8,
                  Ks[bufi] + row * 64 + sc * 8);
      gload_lds16(vt + (((size_t)b * HH + h) * DD + row) * TT + kv0 + gc * 8,
                  VTs[bufi] + row * 64 + sc * 8);
    }
  };
  STAGE(0, 0);
  __syncthreads();  // drains vmcnt before first compute
  int cur = 0;
  for (int kv0 = 0; kv0 < TT; kv0 += 64) {
    if (kv0 + 64 < TT) STAGE(cur ^ 1, kv0 + 64);  // prefetch under compute
    const _Float16* Kc = Ks[cur];
    const _Float16* Vc = VTs[cur];
    // QK^T (scores arrive pre-scaled into exp2 domain via Q)
    f32x4 s[4] = {};
    #pragma unroll
    for (int ks = 0; ks < 2; ++ks)
      #pragma unroll
      for (int ni = 0; ni < 4; ++ni) {
        int row = ni * 16 + lr;
        f16x8 kf = *(const f16x8*)(Kc + row * 64 + (((ks * 4 + lg) ^ (row & 7)) << 3));
        s[ni] = __builtin_amdgcn_mfma_f32_16x16x32_f16(qf[ks], kf, s[ni], 0, 0, 0);
      }
    // defer-max online softmax; q-row = lg*4 + r
    float m4[4];
    int ok = 1;
    #pragma unroll
    for (int r = 0; r < 4; ++r) {
      m4[r] = fmaxf(fmaxf(s[0][r], s[1][r]), fmaxf(s[2][r], s[3][r]));
      ok &= (m4[r] <= mrow[r] + 8.0f) ? 1 : 0;
    }
    if (!__all(ok)) {  // slow path: reduce tile max, rescale o & osum
      #pragma unroll
      for (int r = 0; r < 4; ++r) {
        float rm = m4[r];
        #pragma unroll
        for (int msk = 1; msk <= 8; msk <<= 1) rm = fmaxf(rm, __shfl_xor(rm, msk));
        float mn = fmaxf(mrow[r], rm);
        float corr = exp2f(mrow[r] - mn);
        mrow[r] = mn;
        #pragma unroll
        for (int di = 0; di < 4; ++di) o[di][r] *= corr;
        osum[r] *= corr;
      }
    }
    _Float16* Pw = Ps[w];
    #pragma unroll
    for (int r = 0; r < 4; ++r) {
      float p0 = exp2f(s[0][r] - mrow[r]);
      float p1 = exp2f(s[1][r] - mrow[r]);
      float p2 = exp2f(s[2][r] - mrow[r]);
      float p3 = exp2f(s[3][r] - mrow[r]);
      int prow = lg * 4 + r, rx = prow & 7;
      Pw[prow * 64 + (((0 + (lr >> 3)) ^ rx) << 3) + (lr & 7)] = (_Float16)p0;
      Pw[prow * 64 + (((2 + (lr >> 3)) ^ rx) << 3) + (lr & 7)] = (_Float16)p1;
      Pw[prow * 64 + (((4 + (lr >> 3)) ^ rx) << 3) + (lr & 7)] = (_Float16)p2;
      Pw[prow * 64 + (((6 + (lr >> 3)) ^ rx) << 3) + (lr & 7)] = (_Float16)p3;
    }
    // PV + denominator (Pw per-wave: no barrier; compiler orders ds ops)
    #pragma unroll
    for (int ks = 0; ks < 2; ++ks) {
      f16x8 pf = *(const f16x8*)(Pw + lr * 64 + (((ks * 4 + lg) ^ (lr & 7)) << 3));
      #pragma unroll
      for (int di = 0; di < 4; ++di) {
        int row = di * 16 + lr;
        f16x8 vf = *(const f16x8*)(Vc + row * 64 + (((ks * 4 + lg) ^ (row & 7)) << 3));
        o[di] = __builtin_amdgcn_mfma_f32_16x16x32_f16(pf, vf, o[di], 0, 0, 0);
      }
      osum = __builtin_amdgcn_mfma_f32_16x16x32_f16(pf, ones, osum, 0, 0, 0);
    }
    __syncthreads();  // all waves done with cur; prefetch (vmcnt) drained
    cur ^= 1;
  }
  #pragma unroll
  for (int r = 0; r < 4; ++r) {
    float rinv = 1.0f / osum[r];
    int row_g = qt0 + w * 16 + lg * 4 + r;
    #pragma unroll
    for (int di = 0; di < 4; ++di)
      att[((size_t)(b * TT + row_g)) * CC + h * DD + di * 16 + lr] =
          (_Float16)(o[di][r] * rinv);
  }
}

extern "C" void kernel_launch(void* const* d_in, const int* in_sizes, int n_in,
                              void* d_out, int out_size, void* d_ws, size_t ws_size,
                              hipStream_t stream) {
  const float* x      = (const float*)d_in[0];
  const float* w_qkv  = (const float*)d_in[1];
  const float* b_qkv  = (const float*)d_in[2];
  const float* w_proj = (const float*)d_in[3];
  const float* b_proj = (const float*)d_in[4];
  const float* ln1_g  = (const float*)d_in[5];
  const float* ln1_b  = (const float*)d_in[6];
  const float* w_fc   = (const float*)d_in[7];
  const float* b_fc   = (const float*)d_in[8];
  const float* w_out  = (const float*)d_in[9];
  const float* b_out  = (const float*)d_in[10];
  const float* ln2_g  = (const float*)d_in[11];
  const float* ln2_b  = (const float*)d_in[12];

  char* ws = (char*)d_ws;
  _Float16* wqkv_t = (_Float16*)(ws);              // [3072,1024] 6291456
  _Float16* wproj_t= (_Float16*)(ws + 6291456);    // [1024,1024] -> 8388608
  _Float16* wfc_t  = (_Float16*)(ws + 8388608);    // [4096,1024] -> 16777216
  _Float16* wout_t = (_Float16*)(ws + 16777216);   // [1024,4096] -> 25165824
  _Float16* hslot  = (_Float16*)(ws + 25165824);   // 8388608: h -> att -> h2 (serial reuse)
  _Float16* qbuf   = (_Float16*)(ws + 33554432);   // 8388608
  _Float16* kbuf   = (_Float16*)(ws + 41943040);   // 8388608
  _Float16* vtbuf  = (_Float16*)(ws + 50331648);   // 8388608
  _Float16* tbuf   = (_Float16*)(ws + 33554432);   // [4096,4096] 33554432 (reuses q/k/vt, dead)
  float*    x1     = (float*)(ws + 67108864);      // fp32 16777216 -> 83886080 total

  transpose_cast<<<dim3(96, 32), 256, 0, stream>>>(w_qkv, wqkv_t, 1024, 3072);
  transpose_cast<<<dim3(32, 32), 256, 0, stream>>>(w_proj, wproj_t, 1024, 1024);
  transpose_cast<<<dim3(128, 32), 256, 0, stream>>>(w_fc, wfc_t, 1024, 4096);
  transpose_cast<<<dim3(32, 128), 256, 0, stream>>>(w_out, wout_t, 4096, 1024);

  ln_cast<<<4096, 256, 0, stream>>>(x, ln1_g, ln1_b, hslot);
  gemm_qkv<<<dim3(24, 32), 256, 0, stream>>>(hslot, wqkv_t, b_qkv, qbuf, kbuf, vtbuf);
  flash_attn<<<dim3(32, 16, 2), 256, 0, stream>>>(qbuf, kbuf, vtbuf, hslot);
  gemm_bt<2, 1024, 1024><<<dim3(8, 32), 256, 0, stream>>>(hslot, wproj_t, b_proj, x, x1);
  ln_cast<<<4096, 256, 0, stream>>>(x1, ln2_g, ln2_b, hslot);
  gemm_bt<1, 4096, 1024><<<dim3(32, 32), 256, 0, stream>>>(hslot, wfc_t, b_fc, nullptr, tbuf);
  gemm_bt<2, 1024, 4096><<<dim3(8, 32), 256, 0, stream>>>(tbuf, wout_t, b_out, x1, (float*)d_out);
}

// Round 5
// 313.235 us; speedup vs baseline: 1.4601x; 1.0962x over previous
//
#include <hip/hip_runtime.h>
#include <hip/hip_bf16.h>
#include <math.h>

#define DEVINL static __device__ __forceinline__

typedef _Float16 f16x8 __attribute__((ext_vector_type(8)));
typedef _Float16 f16x4 __attribute__((ext_vector_type(4)));
typedef float f32x4 __attribute__((ext_vector_type(4)));

// B=2, T=2048, C=1024, H=16, D=64
constexpr int TT = 2048, CC = 1024, HH = 16, DD = 64;

DEVINL void gload_lds16(const void* g, void* s) {
  __builtin_amdgcn_global_load_lds(
      (const __attribute__((address_space(1))) void*)g,
      (__attribute__((address_space(3))) void*)s, 16, 0, 0);
}

// ---- weight transpose + cast: fp32 [K,N] -> fp16 [N,K] ----
__global__ __launch_bounds__(256) void transpose_cast(
    const float* __restrict__ in, _Float16* __restrict__ out, int K, int N) {
  __shared__ float tile[32][33];
  int n0 = blockIdx.x * 32, k0 = blockIdx.y * 32;
  int tx = threadIdx.x & 31, ty = threadIdx.x >> 5;  // 32x8
  #pragma unroll
  for (int i = 0; i < 32; i += 8)
    tile[ty + i][tx] = in[(size_t)(k0 + ty + i) * N + n0 + tx];
  __syncthreads();
  #pragma unroll
  for (int i = 0; i < 32; i += 8)
    out[(size_t)(n0 + ty + i) * K + k0 + tx] = (_Float16)tile[tx][ty + i];
}

// ---- LayerNorm -> fp16. One block per row of [4096, 1024]. ----
__global__ __launch_bounds__(256) void ln_cast(
    const float* __restrict__ x, const float* __restrict__ g,
    const float* __restrict__ bta, _Float16* __restrict__ out) {
  int row = blockIdx.x, t = threadIdx.x;
  float4 v = ((const float4*)(x + (size_t)row * CC))[t];
  float s = v.x + v.y + v.z + v.w;
  float s2 = v.x * v.x + v.y * v.y + v.z * v.z + v.w * v.w;
  #pragma unroll
  for (int o = 32; o >= 1; o >>= 1) { s += __shfl_xor(s, o); s2 += __shfl_xor(s2, o); }
  __shared__ float ss[4], ssq[4];
  int w = t >> 6;
  if ((t & 63) == 0) { ss[w] = s; ssq[w] = s2; }
  __syncthreads();
  s = ss[0] + ss[1] + ss[2] + ss[3];
  s2 = ssq[0] + ssq[1] + ssq[2] + ssq[3];
  float mu = s * (1.0f / CC);
  float rs = rsqrtf(s2 * (1.0f / CC) - mu * mu + 1e-5f);
  float4 gv = ((const float4*)g)[t];
  float4 bv = ((const float4*)bta)[t];
  f16x4 o4;
  o4[0] = (_Float16)((v.x - mu) * rs * gv.x + bv.x);
  o4[1] = (_Float16)((v.y - mu) * rs * gv.y + bv.y);
  o4[2] = (_Float16)((v.z - mu) * rs * gv.z + bv.z);
  o4[3] = (_Float16)((v.w - mu) * rs * gv.w + bv.w);
  ((f16x4*)(out + (size_t)row * CC))[t] = o4;
}

// ---- GEMM: C[M,N] = A[M,K](fp16) * Bt[N,K]^T + bias.
// BN=128: 4 waves in 2x2, 64x64 each. BN=64: 4 waves in 4x1, 32x64 each.
// EPI 1: exact GELU -> fp16. EPI 2: + res (fp32) -> fp32.
template <int EPI, int N, int K, int BN>
__global__ __launch_bounds__(256) void gemm_bt(
    const _Float16* __restrict__ A, const _Float16* __restrict__ Bt,
    const float* __restrict__ bias, const float* __restrict__ res,
    void* __restrict__ outp) {
  constexpr int NWN = BN / 64;      // waves along N
  constexpr int MI = 2 * NWN;       // 16-row frags per wave along M
  __shared__ __align__(16) _Float16 As[128 * 64];
  __shared__ __align__(16) _Float16 Bs[BN * 64];
  const int bm0 = blockIdx.y * 128, bn0 = blockIdx.x * BN;
  const int t = threadIdx.x, w = t >> 6, l = t & 63, lg = l >> 4, lr = l & 15;
  const int wr = w / NWN, wc = w % NWN;
  const int srow = t >> 3, sc = t & 7;
  f32x4 acc[MI][4] = {};
  for (int k0 = 0; k0 < K; k0 += 64) {
    #pragma unroll
    for (int q = 0; q < 4; ++q) {
      int row = q * 32 + srow;
      int gc = sc ^ (row & 7);  // inverse-swizzle global source (rule 21)
      gload_lds16(A + (size_t)(bm0 + row) * K + k0 + gc * 8, As + row * 64 + sc * 8);
    }
    #pragma unroll
    for (int q = 0; q < BN / 32; ++q) {
      int row = q * 32 + srow;
      int gc = sc ^ (row & 7);
      gload_lds16(Bt + (size_t)(bn0 + row) * K + k0 + gc * 8, Bs + row * 64 + sc * 8);
    }
    __syncthreads();
    #pragma unroll
    for (int ks = 0; ks < 2; ++ks) {
      f16x8 af[MI], bfr[4];
      #pragma unroll
      for (int mi = 0; mi < MI; ++mi) {
        int row = wr * (16 * MI) + mi * 16 + lr;
        af[mi] = *(const f16x8*)(As + row * 64 + (((ks * 4 + lg) ^ (row & 7)) << 3));
      }
      #pragma unroll
      for (int ni = 0; ni < 4; ++ni) {
        int row = wc * 64 + ni * 16 + lr;
        bfr[ni] = *(const f16x8*)(Bs + row * 64 + (((ks * 4 + lg) ^ (row & 7)) << 3));
      }
      #pragma unroll
      for (int mi = 0; mi < MI; ++mi)
        #pragma unroll
        for (int ni = 0; ni < 4; ++ni)
          acc[mi][ni] = __builtin_amdgcn_mfma_f32_16x16x32_f16(af[mi], bfr[ni], acc[mi][ni], 0, 0, 0);
    }
    __syncthreads();
  }
  #pragma unroll
  for (int mi = 0; mi < MI; ++mi) {
    #pragma unroll
    for (int ni = 0; ni < 4; ++ni) {
      int gc = bn0 + wc * 64 + ni * 16 + lr;
      float bv = bias[gc];
      #pragma unroll
      for (int r = 0; r < 4; ++r) {
        int gr = bm0 + wr * (16 * MI) + mi * 16 + lg * 4 + r;
        float v = acc[mi][ni][r] + bv;
        if constexpr (EPI == 1) {
          float gl = 0.5f * v * (1.0f + erff(v * 0.70710678118654752f));
          ((_Float16*)outp)[(size_t)gr * N + gc] = (_Float16)gl;
        } else {
          ((float*)outp)[(size_t)gr * N + gc] = res[(size_t)gr * N + gc] + v;
        }
      }
    }
  }
}

// ---- QKV GEMM (fp16): writes q[B,T,C] (pre-scaled by 0.125*log2e), k[B,T,C],
// vt[B,H,D,T] ----
__global__ __launch_bounds__(256) void gemm_qkv(
    const _Float16* __restrict__ A, const _Float16* __restrict__ Bt,
    const float* __restrict__ bias,
    _Float16* __restrict__ qo, _Float16* __restrict__ ko,
    _Float16* __restrict__ vt) {
  __shared__ __align__(16) _Float16 As[128 * 64];
  __shared__ __align__(16) _Float16 Bs[128 * 64];
  const int bm0 = blockIdx.y * 128, bn0 = blockIdx.x * 128;
  const int t = threadIdx.x, w = t >> 6, l = t & 63, lg = l >> 4, lr = l & 15;
  const int wr = w >> 1, wc = w & 1;
  const int srow = t >> 3, sc = t & 7;
  f32x4 acc[4][4] = {};
  for (int k0 = 0; k0 < 1024; k0 += 64) {
    #pragma unroll
    for (int q = 0; q < 4; ++q) {
      int row = q * 32 + srow;
      int gc = sc ^ (row & 7);
      gload_lds16(A + (size_t)(bm0 + row) * 1024 + k0 + gc * 8, As + row * 64 + sc * 8);
      gload_lds16(Bt + (size_t)(bn0 + row) * 1024 + k0 + gc * 8, Bs + row * 64 + sc * 8);
    }
    __syncthreads();
    #pragma unroll
    for (int ks = 0; ks < 2; ++ks) {
      f16x8 af[4], bfr[4];
      #pragma unroll
      for (int mi = 0; mi < 4; ++mi) {
        int row = wr * 64 + mi * 16 + lr;
        af[mi] = *(const f16x8*)(As + row * 64 + (((ks * 4 + lg) ^ (row & 7)) << 3));
      }
      #pragma unroll
      for (int ni = 0; ni < 4; ++ni) {
        int row = wc * 64 + ni * 16 + lr;
        bfr[ni] = *(const f16x8*)(Bs + row * 64 + (((ks * 4 + lg) ^ (row & 7)) << 3));
      }
      #pragma unroll
      for (int mi = 0; mi < 4; ++mi)
        #pragma unroll
        for (int ni = 0; ni < 4; ++ni)
          acc[mi][ni] = __builtin_amdgcn_mfma_f32_16x16x32_f16(af[mi], bfr[ni], acc[mi][ni], 0, 0, 0);
    }
    __syncthreads();
  }
  const float QSCL = 0.125f * 1.44269504f;  // fold 1/sqrt(D)*log2(e) into Q
  #pragma unroll
  for (int mi = 0; mi < 4; ++mi) {
    #pragma unroll
    for (int ni = 0; ni < 4; ++ni) {
      int gc = bn0 + wc * 64 + ni * 16 + lr;
      float bv = bias[gc];
      int sec = gc >> 10, cc = gc & 1023;
      #pragma unroll
      for (int r = 0; r < 4; ++r) {
        int gr = bm0 + wr * 64 + mi * 16 + lg * 4 + r;
        float v = acc[mi][ni][r] + bv;
        if (sec == 0) {
          qo[(size_t)gr * 1024 + cc] = (_Float16)(v * QSCL);
        } else if (sec == 1) {
          ko[(size_t)gr * 1024 + cc] = (_Float16)v;
        } else {  // V -> vt[B,H,D,T]
          int hh = cc >> 6, dd = cc & 63;
          int bb = gr >> 11, tk = gr & (TT - 1);
          vt[(((size_t)bb * HH + hh) * DD + dd) * TT + tk] = (_Float16)v;
        }
      }
    }
  }
}

// ---- Flash attention: grid (T/64, H, B); 4 waves x 16 q-rows; Q in regs.
// Defer-max (THR=8 exp2-domain), denominator via ones-MFMA, double-buffered KV,
// all loop-invariant addressing hoisted, launch_bounds(256,4) for VGPR budget.
__global__ __launch_bounds__(256, 4) void flash_attn(
    const _Float16* __restrict__ qg, const _Float16* __restrict__ kg,
    const _Float16* __restrict__ vt, _Float16* __restrict__ att) {
  const int qt0 = blockIdx.x * 64, h = blockIdx.y, b = blockIdx.z;
  const int t = threadIdx.x, w = t >> 6, l = t & 63, lg = l >> 4, lr = l & 15;
  __shared__ __align__(16) _Float16 Ks[2][64 * 64];
  __shared__ __align__(16) _Float16 VTs[2][64 * 64];
  __shared__ __align__(16) _Float16 Ps[4][16 * 64];
  const int srow = t >> 3, sc = t & 7;
  // --- loop-invariant staging addresses: gc = sc ^ (srow&7) (q*32 keeps low 3 bits)
  const int gcs = sc ^ (srow & 7);
  const int dk0 = srow * 64 + sc * 8;
  const _Float16* kg_b = kg + ((size_t)b * TT + srow) * CC + h * DD + gcs * 8;
  const _Float16* vt_b = vt + (((size_t)b * HH + h) * DD + srow) * TT + gcs * 8;
  // --- loop-invariant LDS fragment offsets
  int fro[2][4], pfo[2], pwo[4][4];
  #pragma unroll
  for (int ks = 0; ks < 2; ++ks) {
    #pragma unroll
    for (int ni = 0; ni < 4; ++ni) {
      int row = ni * 16 + lr;
      fro[ks][ni] = row * 64 + (((ks * 4 + lg) ^ (row & 7)) << 3);
    }
    pfo[ks] = lr * 64 + (((ks * 4 + lg) ^ (lr & 7)) << 3);
  }
  #pragma unroll
  for (int r = 0; r < 4; ++r) {
    int prow = lg * 4 + r, rx = prow & 7;
    #pragma unroll
    for (int ni = 0; ni < 4; ++ni)
      pwo[r][ni] = prow * 64 + (((2 * ni + (lr >> 3)) ^ rx) << 3) + (lr & 7);
  }
  // Q fragments in registers (A-operand: row=lr, k-chunk = ks*32+lg*8); pre-scaled.
  f16x8 qf[2];
  #pragma unroll
  for (int ks = 0; ks < 2; ++ks)
    qf[ks] = *(const f16x8*)(qg + ((size_t)(b * TT + qt0 + w * 16 + lr)) * CC +
                             h * DD + ks * 32 + lg * 8);
  f32x4 o[4] = {};
  f32x4 osum = {};  // row-sum via ones-MFMA (rescaled with o)
  float mrow[4];
  #pragma unroll
  for (int r = 0; r < 4; ++r) mrow[r] = -3.0e38f;
  const f16x8 ones = {(_Float16)1, (_Float16)1, (_Float16)1, (_Float16)1,
                      (_Float16)1, (_Float16)1, (_Float16)1, (_Float16)1};

  auto STAGE = [&](int bufi, int kv0) {
    #pragma unroll
    for (int q = 0; q < 2; ++q) {
      gload_lds16(kg_b + (size_t)(kv0 + q * 32) * CC, Ks[bufi] + q * 2048 + dk0);
      gload_lds16(vt_b + q * 32 * TT + kv0, VTs[bufi] + q * 2048 + dk0);
    }
  };
  STAGE(0, 0);
  __syncthreads();  // drains vmcnt before first compute
  int cur = 0;
  for (int kv0 = 0; kv0 < TT; kv0 += 64) {
    if (kv0 + 64 < TT) STAGE(cur ^ 1, kv0 + 64);  // prefetch under compute
    const _Float16* Kc = Ks[cur];
    const _Float16* Vc = VTs[cur];
    // QK^T (scores pre-scaled into exp2 domain via Q)
    f32x4 s[4] = {};
    __builtin_amdgcn_s_setprio(1);
    #pragma unroll
    for (int ks = 0; ks < 2; ++ks)
      #pragma unroll
      for (int ni = 0; ni < 4; ++ni) {
        f16x8 kf = *(const f16x8*)(Kc + fro[ks][ni]);
        s[ni] = __builtin_amdgcn_mfma_f32_16x16x32_f16(qf[ks], kf, s[ni], 0, 0, 0);
      }
    __builtin_amdgcn_s_setprio(0);
    // defer-max online softmax; q-row = lg*4 + r
    float m4[4];
    int ok = 1;
    #pragma unroll
    for (int r = 0; r < 4; ++r) {
      m4[r] = fmaxf(fmaxf(s[0][r], s[1][r]), fmaxf(s[2][r], s[3][r]));
      ok &= (m4[r] <= mrow[r] + 8.0f) ? 1 : 0;
    }
    if (!__all(ok)) {  // slow path: reduce tile max, rescale o & osum
      #pragma unroll
      for (int r = 0; r < 4; ++r) {
        float rm = m4[r];
        #pragma unroll
        for (int msk = 1; msk <= 8; msk <<= 1) rm = fmaxf(rm, __shfl_xor(rm, msk));
        float mn = fmaxf(mrow[r], rm);
        float corr = exp2f(mrow[r] - mn);
        mrow[r] = mn;
        #pragma unroll
        for (int di = 0; di < 4; ++di) o[di][r] *= corr;
        osum[r] *= corr;
      }
    }
    _Float16* Pw = Ps[w];
    #pragma unroll
    for (int r = 0; r < 4; ++r) {
      Pw[pwo[r][0]] = (_Float16)exp2f(s[0][r] - mrow[r]);
      Pw[pwo[r][1]] = (_Float16)exp2f(s[1][r] - mrow[r]);
      Pw[pwo[r][2]] = (_Float16)exp2f(s[2][r] - mrow[r]);
      Pw[pwo[r][3]] = (_Float16)exp2f(s[3][r] - mrow[r]);
    }
    // PV + denominator (Pw per-wave: no barrier; compiler orders ds ops)
    __builtin_amdgcn_s_setprio(1);
    #pragma unroll
    for (int ks = 0; ks < 2; ++ks) {
      f16x8 pf = *(const f16x8*)(Pw + pfo[ks]);
      #pragma unroll
      for (int di = 0; di < 4; ++di) {
        f16x8 vf = *(const f16x8*)(Vc + fro[ks][di]);
        o[di] = __builtin_amdgcn_mfma_f32_16x16x32_f16(pf, vf, o[di], 0, 0, 0);
      }
      osum = __builtin_amdgcn_mfma_f32_16x16x32_f16(pf, ones, osum, 0, 0, 0);
    }
    __builtin_amdgcn_s_setprio(0);
    __syncthreads();  // all waves done with cur; prefetch (vmcnt) drained
    cur ^= 1;
  }
  #pragma unroll
  for (int r = 0; r < 4; ++r) {
    float rinv = 1.0f / osum[r];
    int row_g = qt0 + w * 16 + lg * 4 + r;
    #pragma unroll
    for (int di = 0; di < 4; ++di)
      att[((size_t)(b * TT + row_g)) * CC + h * DD + di * 16 + lr] =
          (_Float16)(o[di][r] * rinv);
  }
}

extern "C" void kernel_launch(void* const* d_in, const int* in_sizes, int n_in,
                              void* d_out, int out_size, void* d_ws, size_t ws_size,
                              hipStream_t stream) {
  const float* x      = (const float*)d_in[0];
  const float* w_qkv  = (const float*)d_in[1];
  const float* b_qkv  = (const float*)d_in[2];
  const float* w_proj = (const float*)d_in[3];
  const float* b_proj = (const float*)d_in[4];
  const float* ln1_g  = (const float*)d_in[5];
  const float* ln1_b  = (const float*)d_in[6];
  const float* w_fc   = (const float*)d_in[7];
  const float* b_fc   = (const float*)d_in[8];
  const float* w_out  = (const float*)d_in[9];
  const float* b_out  = (const float*)d_in[10];
  const float* ln2_g  = (const float*)d_in[11];
  const float* ln2_b  = (const float*)d_in[12];

  char* ws = (char*)d_ws;
  _Float16* wqkv_t = (_Float16*)(ws);              // [3072,1024] 6291456
  _Float16* wproj_t= (_Float16*)(ws + 6291456);    // [1024,1024] -> 8388608
  _Float16* wfc_t  = (_Float16*)(ws + 8388608);    // [4096,1024] -> 16777216
  _Float16* wout_t = (_Float16*)(ws + 16777216);   // [1024,4096] -> 25165824
  _Float16* hslot  = (_Float16*)(ws + 25165824);   // 8388608: h -> att -> h2 (serial reuse)
  _Float16* qbuf   = (_Float16*)(ws + 33554432);   // 8388608
  _Float16* kbuf   = (_Float16*)(ws + 41943040);   // 8388608
  _Float16* vtbuf  = (_Float16*)(ws + 50331648);   // 8388608
  _Float16* tbuf   = (_Float16*)(ws + 33554432);   // [4096,4096] 33554432 (reuses q/k/vt, dead)
  float*    x1     = (float*)(ws + 67108864);      // fp32 16777216 -> 83886080 total

  transpose_cast<<<dim3(96, 32), 256, 0, stream>>>(w_qkv, wqkv_t, 1024, 3072);
  transpose_cast<<<dim3(32, 32), 256, 0, stream>>>(w_proj, wproj_t, 1024, 1024);
  transpose_cast<<<dim3(128, 32), 256, 0, stream>>>(w_fc, wfc_t, 1024, 4096);
  transpose_cast<<<dim3(32, 128), 256, 0, stream>>>(w_out, wout_t, 4096, 1024);

  ln_cast<<<4096, 256, 0, stream>>>(x, ln1_g, ln1_b, hslot);
  gemm_qkv<<<dim3(24, 32), 256, 0, stream>>>(hslot, wqkv_t, b_qkv, qbuf, kbuf, vtbuf);
  flash_attn<<<dim3(32, 16, 2), 256, 0, stream>>>(qbuf, kbuf, vtbuf, hslot);
  gemm_bt<2, 1024, 1024, 64><<<dim3(16, 32), 256, 0, stream>>>(hslot, wproj_t, b_proj, x, x1);
  ln_cast<<<4096, 256, 0, stream>>>(x1, ln2_g, ln2_b, hslot);
  gemm_bt<1, 4096, 1024, 128><<<dim3(32, 32), 256, 0, stream>>>(hslot, wfc_t, b_fc, nullptr, tbuf);
  gemm_bt<2, 1024, 4096, 64><<<dim3(16, 32), 256, 0, stream>>>(tbuf, wout_t, b_out, x1, (float*)d_out);
}